// Round 1
// baseline (433.171 us; speedup 1.0000x reference)
//
#include <hip/hip_runtime.h>
#include <hip/hip_bf16.h>
#include <cstdint>
#include <cmath>

// Problem constants
#define B_    2
#define S_    2048
#define HID_  2048
#define NH_   32
#define HD_   64
#define NQKV  34        // NH + 2
#define FDIM  2176      // NQKV * HD

typedef __attribute__((ext_vector_type(8))) __bf16 bf16x8;
typedef __attribute__((ext_vector_type(4))) float  f32x4;

__device__ __forceinline__ unsigned short f2bf(float f) {
  union { float f; uint32_t u; } v; v.f = f;
  return (unsigned short)((v.u + 0x7FFFu + ((v.u >> 16) & 1u)) >> 16);  // RNE
}
__device__ __forceinline__ float bf2f(unsigned short h) {
  union { uint32_t u; float f; } v; v.u = ((uint32_t)h) << 16;
  return v.f;
}

// async global->LDS, 16B per lane. LDS dest is wave-uniform base + lane*16.
__device__ __forceinline__ void gload_lds16(const void* g, void* lds) {
  __builtin_amdgcn_global_load_lds(
      (const __attribute__((address_space(1))) uint32_t*)(uintptr_t)g,
      (__attribute__((address_space(3))) uint32_t*)(uint32_t)(uintptr_t)lds,
      16, 0, 0);
}

// ---------------- fp32 -> bf16 convert (vectorized) ----------------
__global__ void k_f32_to_bf16(const float* __restrict__ in,
                              unsigned short* __restrict__ out, int n) {
  int i = blockIdx.x * blockDim.x + threadIdx.x;
  int n4 = n >> 2;
  if (i < n4) {
    float4 f = reinterpret_cast<const float4*>(in)[i];
    ushort4 o;
    o.x = f2bf(f.x); o.y = f2bf(f.y); o.z = f2bf(f.z); o.w = f2bf(f.w);
    reinterpret_cast<ushort4*>(out)[i] = o;
  }
}

// ---------------- bf16 GEMM: C[M,N] = A[M,K] * B[N,K]^T ----------------
// m97 structure: 128x128 tile, BK=32, 4 waves, each wave 64x64 (4x4 frags of 16x16x32).
template<int WRITE_BF16>
__global__ __launch_bounds__(256) void k_gemm_bt(const unsigned short* __restrict__ A,
                                                 const unsigned short* __restrict__ Bm,
                                                 void* __restrict__ Cout,
                                                 int M, int N, int K) {
  __shared__ unsigned short As[128][32];   // 8 KB
  __shared__ unsigned short Bs[128][32];   // 8 KB
  const int tid  = threadIdx.x;
  const int lane = tid & 63;
  const int wave = tid >> 6;
  const int wr = wave >> 1, wc = wave & 1;
  const int bm = blockIdx.y, bn = blockIdx.x;

  f32x4 acc[4][4] = {};

  const unsigned short* gA = A  + (size_t)bm * 128 * K;
  const unsigned short* gB = Bm + (size_t)bn * 128 * K;
  const int srow = wave * 16 + (lane >> 2);   // staging row (per round +64)
  const int scol = (lane & 3) * 8;            // staging col (elements)

  for (int k0 = 0; k0 < K; k0 += 32) {
    __syncthreads();   // previous tile fully consumed
#pragma unroll
    for (int r = 0; r < 2; ++r) {
      gload_lds16(gA + (size_t)(srow + r * 64) * K + k0 + scol,
                  (char*)(&As[0][0]) + r * 4096 + wave * 1024);
      gload_lds16(gB + (size_t)(srow + r * 64) * K + k0 + scol,
                  (char*)(&Bs[0][0]) + r * 4096 + wave * 1024);
    }
    __syncthreads();   // drains vmcnt -> tiles ready

    bf16x8 af[4], bfr[4];
#pragma unroll
    for (int i = 0; i < 4; ++i) {
      af[i]  = *reinterpret_cast<const bf16x8*>(&As[wr * 64 + i * 16 + (lane & 15)][(lane >> 4) * 8]);
      bfr[i] = *reinterpret_cast<const bf16x8*>(&Bs[wc * 64 + i * 16 + (lane & 15)][(lane >> 4) * 8]);
    }
#pragma unroll
    for (int i = 0; i < 4; ++i)
#pragma unroll
      for (int j = 0; j < 4; ++j)
        acc[i][j] = __builtin_amdgcn_mfma_f32_16x16x32_bf16(af[i], bfr[j], acc[i][j], 0, 0, 0);
  }

  // C/D layout: col = lane&15, row = (lane>>4)*4 + reg   [m89/m91]
  const int rbase = (lane >> 4) * 4;
  const int cbase = lane & 15;
#pragma unroll
  for (int i = 0; i < 4; ++i)
#pragma unroll
    for (int j = 0; j < 4; ++j)
#pragma unroll
      for (int r = 0; r < 4; ++r) {
        int row = bm * 128 + wr * 64 + i * 16 + rbase + r;
        int col = bn * 128 + wc * 64 + j * 16 + cbase;
        if (WRITE_BF16)
          ((unsigned short*)Cout)[(size_t)row * N + col] = f2bf(acc[i][j][r]);
        else
          ((float*)Cout)[(size_t)row * N + col] = acc[i][j][r];
      }
}

// ---------------- RoPE + split ----------------
// fused (B*S, 34*64) bf16. Heads 0..31 = Q (RoPE, in place), 32 = K (RoPE -> Kr),
// 33 = V (-> Vt transposed (B, 64, S)).
__global__ void k_rope(unsigned short* __restrict__ fused,
                       unsigned short* __restrict__ Kr,
                       unsigned short* __restrict__ Vt) {
  int idx = blockIdx.x * blockDim.x + threadIdx.x;  // (tok, h, i): i in [0,32)
  if (idx >= B_ * S_ * NQKV * 32) return;
  int i   = idx & 31;
  int h   = (idx >> 5) % NQKV;
  int tok = idx / (32 * NQKV);
  int s   = tok & (S_ - 1);
  int b   = tok >> 11;

  unsigned short* src = fused + (size_t)tok * FDIM + h * HD_;
  float x1 = bf2f(src[i]);
  float x2 = bf2f(src[i + 32]);
  float o1, o2;
  if (h <= NH_) {  // q heads + k head
    // angle = s * 10000^(-i/32)
    float ang = (float)s * expf(-(float)i * 0.2878231366242557f /* ln(1e4)/32 */);
    float sn, cs;
    sincosf(ang, &sn, &cs);
    o1 = x1 * cs - x2 * sn;
    o2 = x2 * cs + x1 * sn;
  } else { o1 = x1; o2 = x2; }

  if (h < NH_) {                       // Q in place
    src[i] = f2bf(o1); src[i + 32] = f2bf(o2);
  } else if (h == NH_) {               // K
    unsigned short* dst = Kr + (size_t)tok * HD_;
    dst[i] = f2bf(o1); dst[i + 32] = f2bf(o2);
  } else {                             // V transposed
    Vt[((size_t)b * HD_ + i) * S_ + s]      = f2bf(o1);
    Vt[((size_t)b * HD_ + i + 32) * S_ + s] = f2bf(o2);
  }
}

// ---------------- causal flash attention (MQA) ----------------
// grid (S/64, B*NH). block 256 = 4 waves; wave w handles 16 q rows.
__global__ __launch_bounds__(256) void k_attn(const unsigned short* __restrict__ fused, // Q source
                                              const unsigned short* __restrict__ Kr,
                                              const unsigned short* __restrict__ Vt,
                                              unsigned short* __restrict__ ctx) {
  __shared__ unsigned short Ks[64][64];     // [kv][d]   8 KB
  __shared__ unsigned short Vs[64][64];     // [d][kv]   8 KB
  __shared__ unsigned short Ps[4][16][64];  // per-wave P tile  8 KB
  const int tid  = threadIdx.x;
  const int lane = tid & 63;
  const int wave = tid >> 6;
  const int q0   = blockIdx.x * 64;
  const int bh   = blockIdx.y;
  const int b    = bh >> 5;
  const int h    = bh & 31;
  const int rbase = (lane >> 4) * 4;
  const int cidx  = lane & 15;

  // Q fragments (A operand): row = lane%16, k-chunk = (lane>>4)*8
  const unsigned short* qbase =
      fused + ((size_t)(b * S_ + q0 + wave * 16 + cidx)) * FDIM + h * HD_;
  bf16x8 aq0 = *reinterpret_cast<const bf16x8*>(qbase + (lane >> 4) * 8);
  bf16x8 aq1 = *reinterpret_cast<const bf16x8*>(qbase + 32 + (lane >> 4) * 8);

  f32x4 oacc[4] = {};
  float mrun[4], lsum[4];
#pragma unroll
  for (int r = 0; r < 4; ++r) { mrun[r] = -1e30f; lsum[r] = 0.f; }

  const int srow = wave * 8 + (lane >> 3);  // staging row per round (+32)
  const int scol = (lane & 7) * 8;
  const int nt = q0 / 64 + 1;

  for (int t = 0; t < nt; ++t) {
    const int kv0 = t * 64;
    __syncthreads();
#pragma unroll
    for (int r = 0; r < 2; ++r) {
      gload_lds16(Kr + ((size_t)(b * S_ + kv0 + r * 32 + srow)) * HD_ + scol,
                  (char*)(&Ks[0][0]) + r * 4096 + wave * 1024);
      gload_lds16(Vt + ((size_t)(b * HD_ + r * 32 + srow)) * S_ + kv0 + scol,
                  (char*)(&Vs[0][0]) + r * 4096 + wave * 1024);
    }
    __syncthreads();

    // S = Q K^T * 0.125, causal masked
    f32x4 sacc[4];
#pragma unroll
    for (int ni = 0; ni < 4; ++ni) {
      bf16x8 bk0 = *reinterpret_cast<const bf16x8*>(&Ks[ni * 16 + cidx][(lane >> 4) * 8]);
      bf16x8 bk1 = *reinterpret_cast<const bf16x8*>(&Ks[ni * 16 + cidx][32 + (lane >> 4) * 8]);
      f32x4 z = {};
      z = __builtin_amdgcn_mfma_f32_16x16x32_bf16(aq0, bk0, z, 0, 0, 0);
      z = __builtin_amdgcn_mfma_f32_16x16x32_bf16(aq1, bk1, z, 0, 0, 0);
      sacc[ni] = z;
    }

    float tmax[4];
#pragma unroll
    for (int r = 0; r < 4; ++r) {
      int row = q0 + wave * 16 + rbase + r;
      float mx = -1e30f;
#pragma unroll
      for (int ni = 0; ni < 4; ++ni) {
        int col = kv0 + ni * 16 + cidx;
        float v = sacc[ni][r] * 0.125f;
        v = (col <= row) ? v : -1e30f;
        sacc[ni][r] = v;
        mx = fmaxf(mx, v);
      }
#pragma unroll
      for (int off = 1; off < 16; off <<= 1)
        mx = fmaxf(mx, __shfl_xor(mx, off));
      tmax[r] = mx;
    }

#pragma unroll
    for (int r = 0; r < 4; ++r) {
      float mnew = fmaxf(mrun[r], tmax[r]);
      float corr = __expf(mrun[r] - mnew);
      mrun[r] = mnew;
      float rsum = 0.f;
#pragma unroll
      for (int ni = 0; ni < 4; ++ni) {
        float p = __expf(sacc[ni][r] - mnew);
        sacc[ni][r] = p;
        rsum += p;
      }
#pragma unroll
      for (int off = 1; off < 16; off <<= 1)
        rsum += __shfl_xor(rsum, off);
      lsum[r] = lsum[r] * corr + rsum;
#pragma unroll
      for (int di = 0; di < 4; ++di)
        oacc[di][r] *= corr;
    }

    // P -> LDS (re-layout for A operand), wave-private region
#pragma unroll
    for (int ni = 0; ni < 4; ++ni)
#pragma unroll
      for (int r = 0; r < 4; ++r)
        Ps[wave][rbase + r][ni * 16 + cidx] = f2bf(sacc[ni][r]);

    bf16x8 ap0 = *reinterpret_cast<const bf16x8*>(&Ps[wave][cidx][(lane >> 4) * 8]);
    bf16x8 ap1 = *reinterpret_cast<const bf16x8*>(&Ps[wave][cidx][32 + (lane >> 4) * 8]);
#pragma unroll
    for (int di = 0; di < 4; ++di) {
      bf16x8 bv0 = *reinterpret_cast<const bf16x8*>(&Vs[di * 16 + cidx][(lane >> 4) * 8]);
      bf16x8 bv1 = *reinterpret_cast<const bf16x8*>(&Vs[di * 16 + cidx][32 + (lane >> 4) * 8]);
      oacc[di] = __builtin_amdgcn_mfma_f32_16x16x32_bf16(ap0, bv0, oacc[di], 0, 0, 0);
      oacc[di] = __builtin_amdgcn_mfma_f32_16x16x32_bf16(ap1, bv1, oacc[di], 0, 0, 0);
    }
  }

  // epilogue: ctx[b, s, h*64+d] = O / l
#pragma unroll
  for (int di = 0; di < 4; ++di)
#pragma unroll
    for (int r = 0; r < 4; ++r) {
      int row = q0 + wave * 16 + rbase + r;
      int d   = di * 16 + cidx;
      ctx[((size_t)(b * S_ + row)) * HID_ + h * HD_ + d] = f2bf(oacc[di][r] / lsum[r]);
    }
}

// ---------------- launch ----------------
extern "C" void kernel_launch(void* const* d_in, const int* in_sizes, int n_in,
                              void* d_out, int out_size, void* d_ws, size_t ws_size,
                              hipStream_t stream) {
  const float* hidden  = (const float*)d_in[0];
  const float* w_qkv   = (const float*)d_in[1];
  const float* w_dense = (const float*)d_in[2];
  char* ws = (char*)d_ws;

  // workspace layout (bytes)
  unsigned short* Xb  = (unsigned short*)(ws + 0);          // 4096x2048 bf16 (reused as ctx)
  unsigned short* Wqb = (unsigned short*)(ws + 16777216);   // 2176x2048 bf16
  unsigned short* Wdb = (unsigned short*)(ws + 25690112);   // 2048x2048 bf16
  unsigned short* Fb  = (unsigned short*)(ws + 34078720);   // 4096x2176 bf16 (fused QKV)
  unsigned short* Kr  = (unsigned short*)(ws + 51904512);   // 2x2048x64 bf16
  unsigned short* Vt  = (unsigned short*)(ws + 52428800);   // 2x64x2048 bf16

  const int n1 = B_ * S_ * HID_;   // 8388608
  const int n2 = FDIM * HID_;      // 4456448
  const int n3 = HID_ * HID_;      // 4194304
  k_f32_to_bf16<<<dim3((n1 / 4 + 255) / 256), 256, 0, stream>>>(hidden, Xb, n1);
  k_f32_to_bf16<<<dim3((n2 / 4 + 255) / 256), 256, 0, stream>>>(w_qkv, Wqb, n2);
  k_f32_to_bf16<<<dim3((n3 / 4 + 255) / 256), 256, 0, stream>>>(w_dense, Wdb, n3);

  // fused = X @ Wqkv^T  (M=4096, N=2176, K=2048), bf16 out
  k_gemm_bt<1><<<dim3(FDIM / 128, (B_ * S_) / 128), 256, 0, stream>>>(
      Xb, Wqb, (void*)Fb, B_ * S_, FDIM, HID_);

  // RoPE (Q in place, K->Kr, V->Vt)
  const int nrope = B_ * S_ * NQKV * 32;
  k_rope<<<dim3(nrope / 256), 256, 0, stream>>>(Fb, Kr, Vt);

  // attention -> ctx (reuses Xb)
  k_attn<<<dim3(S_ / 64, B_ * NH_), 256, 0, stream>>>(Fb, Kr, Vt, Xb);

  // out = ctx @ Wd^T  (M=4096, N=2048, K=2048), fp32 out
  k_gemm_bt<0><<<dim3(HID_ / 128, (B_ * S_) / 128), 256, 0, stream>>>(
      Xb, Wdb, d_out, B_ * S_, HID_, HID_);
}

// Round 2
// 398.052 us; speedup vs baseline: 1.0882x; 1.0882x over previous
//
#include <hip/hip_runtime.h>
#include <hip/hip_bf16.h>
#include <cstdint>
#include <cmath>

// Problem constants
#define B_    2
#define S_    2048
#define HID_  2048
#define NH_   32
#define HD_   64
#define NQKV  34        // NH + 2
#define FDIM  2176      // NQKV * HD

typedef __attribute__((ext_vector_type(8))) __bf16 bf16x8;
typedef __attribute__((ext_vector_type(4))) float  f32x4;

__device__ __forceinline__ unsigned short f2bf(float f) {
  union { float f; uint32_t u; } v; v.f = f;
  return (unsigned short)((v.u + 0x7FFFu + ((v.u >> 16) & 1u)) >> 16);  // RNE
}
__device__ __forceinline__ float bf2f(unsigned short h) {
  union { uint32_t u; float f; } v; v.u = ((uint32_t)h) << 16;
  return v.f;
}

// async global->LDS, 16B per lane. LDS dest is wave-uniform base + lane*16.
__device__ __forceinline__ void gload_lds16(const void* g, void* lds) {
  __builtin_amdgcn_global_load_lds(
      (const __attribute__((address_space(1))) uint32_t*)(uintptr_t)g,
      (__attribute__((address_space(3))) uint32_t*)(uint32_t)(uintptr_t)lds,
      16, 0, 0);
}

// swizzled LDS 16B read from a [rows][64] bf16 tile (128B rows):
// chunk c in [0,8), actual chunk = c ^ (row&7)
__device__ __forceinline__ bf16x8 lds_rd_swz(const unsigned short* tile, int row, int c) {
  return *reinterpret_cast<const bf16x8*>(
      reinterpret_cast<const char*>(tile) + row * 128 + ((c ^ (row & 7)) << 4));
}

// ---------------- fp32 -> bf16 convert (vectorized) ----------------
__global__ void k_f32_to_bf16(const float* __restrict__ in,
                              unsigned short* __restrict__ out, int n) {
  int i = blockIdx.x * blockDim.x + threadIdx.x;
  int n4 = n >> 2;
  if (i < n4) {
    float4 f = reinterpret_cast<const float4*>(in)[i];
    ushort4 o;
    o.x = f2bf(f.x); o.y = f2bf(f.y); o.z = f2bf(f.z); o.w = f2bf(f.w);
    reinterpret_cast<ushort4*>(out)[i] = o;
  }
}

// ---------------- bf16 GEMM: C[M,N] = A[M,K] * B[N,K]^T ----------------
// m97 structure: 128x128 tile, BK=32, 4 waves, each wave 64x64 (4x4 frags of 16x16x32).
template<int WRITE_BF16>
__global__ __launch_bounds__(256) void k_gemm_bt(const unsigned short* __restrict__ A,
                                                 const unsigned short* __restrict__ Bm,
                                                 void* __restrict__ Cout,
                                                 int M, int N, int K) {
  __shared__ unsigned short As[128][32];   // 8 KB
  __shared__ unsigned short Bs[128][32];   // 8 KB
  const int tid  = threadIdx.x;
  const int lane = tid & 63;
  const int wave = tid >> 6;
  const int wr = wave >> 1, wc = wave & 1;
  const int bm = blockIdx.y, bn = blockIdx.x;

  f32x4 acc[4][4] = {};

  const unsigned short* gA = A  + (size_t)bm * 128 * K;
  const unsigned short* gB = Bm + (size_t)bn * 128 * K;
  const int srow = wave * 16 + (lane >> 2);   // staging row (per round +64)
  const int scol = (lane & 3) * 8;            // staging col (elements)

  for (int k0 = 0; k0 < K; k0 += 32) {
    __syncthreads();   // previous tile fully consumed
#pragma unroll
    for (int r = 0; r < 2; ++r) {
      gload_lds16(gA + (size_t)(srow + r * 64) * K + k0 + scol,
                  (char*)(&As[0][0]) + r * 4096 + wave * 1024);
      gload_lds16(gB + (size_t)(srow + r * 64) * K + k0 + scol,
                  (char*)(&Bs[0][0]) + r * 4096 + wave * 1024);
    }
    __syncthreads();   // drains vmcnt -> tiles ready

    bf16x8 af[4], bfr[4];
#pragma unroll
    for (int i = 0; i < 4; ++i) {
      af[i]  = *reinterpret_cast<const bf16x8*>(&As[wr * 64 + i * 16 + (lane & 15)][(lane >> 4) * 8]);
      bfr[i] = *reinterpret_cast<const bf16x8*>(&Bs[wc * 64 + i * 16 + (lane & 15)][(lane >> 4) * 8]);
    }
#pragma unroll
    for (int i = 0; i < 4; ++i)
#pragma unroll
      for (int j = 0; j < 4; ++j)
        acc[i][j] = __builtin_amdgcn_mfma_f32_16x16x32_bf16(af[i], bfr[j], acc[i][j], 0, 0, 0);
  }

  // C/D layout: col = lane&15, row = (lane>>4)*4 + reg   [m89/m91]
  const int rbase = (lane >> 4) * 4;
  const int cbase = lane & 15;
#pragma unroll
  for (int i = 0; i < 4; ++i)
#pragma unroll
    for (int j = 0; j < 4; ++j)
#pragma unroll
      for (int r = 0; r < 4; ++r) {
        int row = bm * 128 + wr * 64 + i * 16 + rbase + r;
        int col = bn * 128 + wc * 64 + j * 16 + cbase;
        if (WRITE_BF16)
          ((unsigned short*)Cout)[(size_t)row * N + col] = f2bf(acc[i][j][r]);
        else
          ((float*)Cout)[(size_t)row * N + col] = acc[i][j][r];
      }
}

// ---------------- RoPE + split ----------------
__global__ void k_rope(unsigned short* __restrict__ fused,
                       unsigned short* __restrict__ Kr,
                       unsigned short* __restrict__ Vt) {
  int idx = blockIdx.x * blockDim.x + threadIdx.x;  // (tok, h, i): i in [0,32)
  if (idx >= B_ * S_ * NQKV * 32) return;
  int i   = idx & 31;
  int h   = (idx >> 5) % NQKV;
  int tok = idx / (32 * NQKV);
  int s   = tok & (S_ - 1);
  int b   = tok >> 11;

  unsigned short* src = fused + (size_t)tok * FDIM + h * HD_;
  float x1 = bf2f(src[i]);
  float x2 = bf2f(src[i + 32]);
  float o1, o2;
  if (h <= NH_) {  // q heads + k head
    float ang = (float)s * expf(-(float)i * 0.2878231366242557f /* ln(1e4)/32 */);
    float sn, cs;
    sincosf(ang, &sn, &cs);
    o1 = x1 * cs - x2 * sn;
    o2 = x2 * cs + x1 * sn;
  } else { o1 = x1; o2 = x2; }

  if (h < NH_) {                       // Q in place
    src[i] = f2bf(o1); src[i + 32] = f2bf(o2);
  } else if (h == NH_) {               // K
    unsigned short* dst = Kr + (size_t)tok * HD_;
    dst[i] = f2bf(o1); dst[i + 32] = f2bf(o2);
  } else {                             // V transposed
    Vt[((size_t)b * HD_ + i) * S_ + s]      = f2bf(o1);
    Vt[((size_t)b * HD_ + i + 32) * S_ + s] = f2bf(o2);
  }
}

// ---------------- causal flash attention (MQA) ----------------
// grid (S/128, B*NH). block 256 = 4 waves; wave w owns 32 q rows (2 row-groups of 16).
// K/V LDS tiles XOR-swizzled (staged via pre-swizzled global source, read swizzled).
__global__ __launch_bounds__(256) void k_attn(const unsigned short* __restrict__ fused,
                                              const unsigned short* __restrict__ Kr,
                                              const unsigned short* __restrict__ Vt,
                                              unsigned short* __restrict__ ctx) {
  __shared__ unsigned short Ks[64 * 64];     // [kv][d]   8 KB, swizzled
  __shared__ unsigned short Vs[64 * 64];     // [d][kv]   8 KB, swizzled
  __shared__ unsigned short Ps[4][16 * 64];  // per-wave P tile 8 KB, swizzled
  const int tid  = threadIdx.x;
  const int lane = tid & 63;
  const int w    = tid >> 6;
  const int qt   = gridDim.x - 1 - blockIdx.x;  // heavy tiles first
  const int q0   = qt * 128;
  const int bh   = blockIdx.y;
  const int b    = bh >> 5;
  const int h    = bh & 31;
  const int g    = lane >> 4;     // lane group 0..3
  const int cidx = lane & 15;
  const int rbase = g * 4;

  // Q fragments: aq[rg][c]: row q0 + w*32 + rg*16 + cidx, k-chunk c*32 + g*8
  bf16x8 aq[2][2];
#pragma unroll
  for (int rg = 0; rg < 2; ++rg) {
    const unsigned short* qb =
        fused + ((size_t)(b * S_ + q0 + w * 32 + rg * 16 + cidx)) * FDIM + h * HD_ + g * 8;
    aq[rg][0] = *reinterpret_cast<const bf16x8*>(qb);
    aq[rg][1] = *reinterpret_cast<const bf16x8*>(qb + 32);
  }

  f32x4 oacc[2][4] = {};
  float mrun[2][4], lsum[2][4];
#pragma unroll
  for (int rg = 0; rg < 2; ++rg)
#pragma unroll
    for (int r = 0; r < 4; ++r) { mrun[rg][r] = -1e30f; lsum[rg][r] = 0.f; }

  // staging: per round (32 rows), wave w stages rows r*32 + w*8 + sr, swizzled source chunk
  const int sr = lane >> 3;                       // 0..7
  const int sc = (((lane & 7) ^ sr)) * 8;         // source element offset (swizzle)

  const int nt = q0 / 64 + 2;
  for (int t = 0; t < nt; ++t) {
    const int kv0 = t * 64;
    __syncthreads();
#pragma unroll
    for (int r = 0; r < 2; ++r) {
      int row = r * 32 + w * 8 + sr;
      gload_lds16(Kr + ((size_t)(b * S_ + kv0 + row)) * HD_ + sc,
                  (char*)Ks + r * 4096 + w * 1024);
      gload_lds16(Vt + ((size_t)(b * HD_ + row)) * S_ + kv0 + sc,
                  (char*)Vs + r * 4096 + w * 1024);
    }
    __syncthreads();

#pragma unroll
    for (int rg = 0; rg < 2; ++rg) {
      const int rowTop = q0 + w * 32 + rg * 16;
      if (kv0 > rowTop + 15) continue;   // fully masked row-group (wave-uniform)

      // S = Q K^T
      f32x4 sacc[4];
      __builtin_amdgcn_s_setprio(1);
#pragma unroll
      for (int ni = 0; ni < 4; ++ni) {
        int krow = ni * 16 + cidx;
        bf16x8 bk0 = lds_rd_swz(Ks, krow, g);
        bf16x8 bk1 = lds_rd_swz(Ks, krow, 4 + g);
        f32x4 z = {};
        z = __builtin_amdgcn_mfma_f32_16x16x32_bf16(aq[rg][0], bk0, z, 0, 0, 0);
        z = __builtin_amdgcn_mfma_f32_16x16x32_bf16(aq[rg][1], bk1, z, 0, 0, 0);
        sacc[ni] = z;
      }
      __builtin_amdgcn_s_setprio(0);

      const bool needMask = (kv0 + 63 > rowTop);  // wave-uniform
      float tmax[4];
#pragma unroll
      for (int r = 0; r < 4; ++r) {
        int row = rowTop + rbase + r;
        float mx = -1e30f;
        if (needMask) {
#pragma unroll
          for (int ni = 0; ni < 4; ++ni) {
            int col = kv0 + ni * 16 + cidx;
            float v = sacc[ni][r] * 0.125f;
            v = (col <= row) ? v : -1e30f;
            sacc[ni][r] = v;
            mx = fmaxf(mx, v);
          }
        } else {
#pragma unroll
          for (int ni = 0; ni < 4; ++ni) {
            float v = sacc[ni][r] * 0.125f;
            sacc[ni][r] = v;
            mx = fmaxf(mx, v);
          }
        }
#pragma unroll
        for (int off = 1; off < 16; off <<= 1)
          mx = fmaxf(mx, __shfl_xor(mx, off));
        tmax[r] = mx;
      }

      // defer-max (T13): skip O-rescale if max didn't grow past threshold
      bool ok = true;
#pragma unroll
      for (int r = 0; r < 4; ++r) ok = ok && (tmax[r] <= mrun[rg][r] + 8.0f);
      if (__all(ok)) {
#pragma unroll
        for (int r = 0; r < 4; ++r) {
          float m = mrun[rg][r];
          float rsum = 0.f;
#pragma unroll
          for (int ni = 0; ni < 4; ++ni) {
            float p = __expf(sacc[ni][r] - m);
            sacc[ni][r] = p;
            rsum += p;
          }
#pragma unroll
          for (int off = 1; off < 16; off <<= 1)
            rsum += __shfl_xor(rsum, off);
          lsum[rg][r] += rsum;
        }
      } else {
#pragma unroll
        for (int r = 0; r < 4; ++r) {
          float mnew = fmaxf(mrun[rg][r], tmax[r]);
          float corr = __expf(mrun[rg][r] - mnew);
          mrun[rg][r] = mnew;
          float rsum = 0.f;
#pragma unroll
          for (int ni = 0; ni < 4; ++ni) {
            float p = __expf(sacc[ni][r] - mnew);
            sacc[ni][r] = p;
            rsum += p;
          }
#pragma unroll
          for (int off = 1; off < 16; off <<= 1)
            rsum += __shfl_xor(rsum, off);
          lsum[rg][r] = lsum[rg][r] * corr + rsum;
#pragma unroll
          for (int di = 0; di < 4; ++di)
            oacc[rg][di][r] *= corr;
        }
      }

      // P -> wave-private LDS (swizzled), then read back as A operand
      unsigned short* Pw = Ps[w];
#pragma unroll
      for (int ni = 0; ni < 4; ++ni)
#pragma unroll
        for (int r = 0; r < 4; ++r) {
          int prow = rbase + r;
          int col  = ni * 16 + cidx;
          Pw[prow * 64 + (col ^ ((prow & 7) << 3))] = f2bf(sacc[ni][r]);
        }
      bf16x8 ap0 = *reinterpret_cast<const bf16x8*>(&Pw[cidx * 64 + ((g ^ (cidx & 7)) << 3)]);
      bf16x8 ap1 = *reinterpret_cast<const bf16x8*>(&Pw[cidx * 64 + (((4 + g) ^ (cidx & 7)) << 3)]);

      __builtin_amdgcn_s_setprio(1);
#pragma unroll
      for (int di = 0; di < 4; ++di) {
        int vrow = di * 16 + cidx;
        bf16x8 bv0 = lds_rd_swz(Vs, vrow, g);
        bf16x8 bv1 = lds_rd_swz(Vs, vrow, 4 + g);
        oacc[rg][di] = __builtin_amdgcn_mfma_f32_16x16x32_bf16(ap0, bv0, oacc[rg][di], 0, 0, 0);
        oacc[rg][di] = __builtin_amdgcn_mfma_f32_16x16x32_bf16(ap1, bv1, oacc[rg][di], 0, 0, 0);
      }
      __builtin_amdgcn_s_setprio(0);
    }
  }

  // epilogue: ctx[b, s, h*64+d] = O / l
#pragma unroll
  for (int rg = 0; rg < 2; ++rg)
#pragma unroll
    for (int di = 0; di < 4; ++di)
#pragma unroll
      for (int r = 0; r < 4; ++r) {
        int row = q0 + w * 32 + rg * 16 + rbase + r;
        int d   = di * 16 + cidx;
        ctx[((size_t)(b * S_ + row)) * HID_ + h * HD_ + d] =
            f2bf(oacc[rg][di][r] / lsum[rg][r]);
      }
}

// ---------------- launch ----------------
extern "C" void kernel_launch(void* const* d_in, const int* in_sizes, int n_in,
                              void* d_out, int out_size, void* d_ws, size_t ws_size,
                              hipStream_t stream) {
  const float* hidden  = (const float*)d_in[0];
  const float* w_qkv   = (const float*)d_in[1];
  const float* w_dense = (const float*)d_in[2];
  char* ws = (char*)d_ws;

  // workspace layout (bytes)
  unsigned short* Xb  = (unsigned short*)(ws + 0);          // 4096x2048 bf16 (reused as ctx)
  unsigned short* Wqb = (unsigned short*)(ws + 16777216);   // 2176x2048 bf16
  unsigned short* Wdb = (unsigned short*)(ws + 25690112);   // 2048x2048 bf16
  unsigned short* Fb  = (unsigned short*)(ws + 34078720);   // 4096x2176 bf16 (fused QKV)
  unsigned short* Kr  = (unsigned short*)(ws + 51904512);   // 2x2048x64 bf16
  unsigned short* Vt  = (unsigned short*)(ws + 52428800);   // 2x64x2048 bf16

  const int n1 = B_ * S_ * HID_;   // 8388608
  const int n2 = FDIM * HID_;      // 4456448
  const int n3 = HID_ * HID_;      // 4194304
  k_f32_to_bf16<<<dim3((n1 / 4 + 255) / 256), 256, 0, stream>>>(hidden, Xb, n1);
  k_f32_to_bf16<<<dim3((n2 / 4 + 255) / 256), 256, 0, stream>>>(w_qkv, Wqb, n2);
  k_f32_to_bf16<<<dim3((n3 / 4 + 255) / 256), 256, 0, stream>>>(w_dense, Wdb, n3);

  // fused = X @ Wqkv^T  (M=4096, N=2176, K=2048), bf16 out
  k_gemm_bt<1><<<dim3(FDIM / 128, (B_ * S_) / 128), 256, 0, stream>>>(
      Xb, Wqb, (void*)Fb, B_ * S_, FDIM, HID_);

  // RoPE (Q in place, K->Kr, V->Vt)
  const int nrope = B_ * S_ * NQKV * 32;
  k_rope<<<dim3(nrope / 256), 256, 0, stream>>>(Fb, Kr, Vt);

  // attention -> ctx (reuses Xb)
  k_attn<<<dim3(S_ / 128, B_ * NH_), 256, 0, stream>>>(Fb, Kr, Vt, Xb);

  // out = ctx @ Wd^T  (M=4096, N=2048, K=2048), fp32 out
  k_gemm_bt<0><<<dim3(HID_ / 128, (B_ * S_) / 128), 256, 0, stream>>>(
      Xb, Wdb, d_out, B_ * S_, HID_, HID_);
}

// Round 3
// 294.831 us; speedup vs baseline: 1.4692x; 1.3501x over previous
//
#include <hip/hip_runtime.h>
#include <hip/hip_bf16.h>
#include <cstdint>
#include <cmath>

// Problem constants
#define B_    2
#define S_    2048
#define HID_  2048
#define NH_   32
#define HD_   64
#define NQKV  34        // NH + 2
#define FDIM  2176      // NQKV * HD

typedef __attribute__((ext_vector_type(8))) __bf16 bf16x8;
typedef __attribute__((ext_vector_type(4))) float  f32x4;

__device__ __forceinline__ unsigned short f2bf(float f) {
  union { float f; uint32_t u; } v; v.f = f;
  return (unsigned short)((v.u + 0x7FFFu + ((v.u >> 16) & 1u)) >> 16);  // RNE
}
__device__ __forceinline__ float bf2f(unsigned short h) {
  union { uint32_t u; float f; } v; v.u = ((uint32_t)h) << 16;
  return v.f;
}

// async global->LDS, 16B per lane. LDS dest is wave-uniform base + lane*16.
__device__ __forceinline__ void gload_lds16(const void* g, void* lds) {
  __builtin_amdgcn_global_load_lds(
      (const __attribute__((address_space(1))) uint32_t*)(uintptr_t)g,
      (__attribute__((address_space(3))) uint32_t*)(uint32_t)(uintptr_t)lds,
      16, 0, 0);
}

// swizzled LDS 16B read from a [rows][64] bf16 tile (128B rows):
// chunk c in [0,8), actual chunk = c ^ (row&7)
__device__ __forceinline__ bf16x8 lds_rd_swz(const unsigned short* tile, int row, int c) {
  return *reinterpret_cast<const bf16x8*>(
      reinterpret_cast<const char*>(tile) + row * 128 + ((c ^ (row & 7)) << 4));
}

// ---------------- fp32 -> bf16 convert (vectorized) ----------------
__global__ void k_f32_to_bf16(const float* __restrict__ in,
                              unsigned short* __restrict__ out, int n) {
  int i = blockIdx.x * blockDim.x + threadIdx.x;
  int n4 = n >> 2;
  if (i < n4) {
    float4 f = reinterpret_cast<const float4*>(in)[i];
    ushort4 o;
    o.x = f2bf(f.x); o.y = f2bf(f.y); o.z = f2bf(f.z); o.w = f2bf(f.w);
    reinterpret_cast<ushort4*>(out)[i] = o;
  }
}

// ---------------- bf16 GEMM: C[M,N] = A[M,K] * B[N,K]^T ----------------
template<int WRITE_BF16>
__global__ __launch_bounds__(256) void k_gemm_bt(const unsigned short* __restrict__ A,
                                                 const unsigned short* __restrict__ Bm,
                                                 void* __restrict__ Cout,
                                                 int M, int N, int K) {
  __shared__ unsigned short As[128][32];   // 8 KB
  __shared__ unsigned short Bs[128][32];   // 8 KB
  const int tid  = threadIdx.x;
  const int lane = tid & 63;
  const int wave = tid >> 6;
  const int wr = wave >> 1, wc = wave & 1;
  const int bm = blockIdx.y, bn = blockIdx.x;

  f32x4 acc[4][4] = {};

  const unsigned short* gA = A  + (size_t)bm * 128 * K;
  const unsigned short* gB = Bm + (size_t)bn * 128 * K;
  const int srow = wave * 16 + (lane >> 2);
  const int scol = (lane & 3) * 8;

  for (int k0 = 0; k0 < K; k0 += 32) {
    __syncthreads();
#pragma unroll
    for (int r = 0; r < 2; ++r) {
      gload_lds16(gA + (size_t)(srow + r * 64) * K + k0 + scol,
                  (char*)(&As[0][0]) + r * 4096 + wave * 1024);
      gload_lds16(gB + (size_t)(srow + r * 64) * K + k0 + scol,
                  (char*)(&Bs[0][0]) + r * 4096 + wave * 1024);
    }
    __syncthreads();

    bf16x8 af[4], bfr[4];
#pragma unroll
    for (int i = 0; i < 4; ++i) {
      af[i]  = *reinterpret_cast<const bf16x8*>(&As[wr * 64 + i * 16 + (lane & 15)][(lane >> 4) * 8]);
      bfr[i] = *reinterpret_cast<const bf16x8*>(&Bs[wc * 64 + i * 16 + (lane & 15)][(lane >> 4) * 8]);
    }
#pragma unroll
    for (int i = 0; i < 4; ++i)
#pragma unroll
      for (int j = 0; j < 4; ++j)
        acc[i][j] = __builtin_amdgcn_mfma_f32_16x16x32_bf16(af[i], bfr[j], acc[i][j], 0, 0, 0);
  }

  const int rbase = (lane >> 4) * 4;
  const int cbase = lane & 15;
#pragma unroll
  for (int i = 0; i < 4; ++i)
#pragma unroll
    for (int j = 0; j < 4; ++j)
#pragma unroll
      for (int r = 0; r < 4; ++r) {
        int row = bm * 128 + wr * 64 + i * 16 + rbase + r;
        int col = bn * 128 + wc * 64 + j * 16 + cbase;
        if (WRITE_BF16)
          ((unsigned short*)Cout)[(size_t)row * N + col] = f2bf(acc[i][j][r]);
        else
          ((float*)Cout)[(size_t)row * N + col] = acc[i][j][r];
      }
}

// ---------------- RoPE + split ----------------
// Q additionally pre-scaled by 0.125*log2(e) so attention softmax can use raw exp2.
__global__ void k_rope(unsigned short* __restrict__ fused,
                       unsigned short* __restrict__ Kr,
                       unsigned short* __restrict__ Vt) {
  int idx = blockIdx.x * blockDim.x + threadIdx.x;  // (tok, h, i): i in [0,32)
  if (idx >= B_ * S_ * NQKV * 32) return;
  int i   = idx & 31;
  int h   = (idx >> 5) % NQKV;
  int tok = idx / (32 * NQKV);
  int s   = tok & (S_ - 1);
  int b   = tok >> 11;

  unsigned short* src = fused + (size_t)tok * FDIM + h * HD_;
  float x1 = bf2f(src[i]);
  float x2 = bf2f(src[i + 32]);
  float o1, o2;
  if (h <= NH_) {  // q heads + k head
    float ang = (float)s * expf(-(float)i * 0.2878231366242557f /* ln(1e4)/32 */);
    float sn, cs;
    sincosf(ang, &sn, &cs);
    o1 = x1 * cs - x2 * sn;
    o2 = x2 * cs + x1 * sn;
  } else { o1 = x1; o2 = x2; }

  if (h < NH_) {                       // Q in place, folded softmax scale
    const float QSCL = 0.18033688011112042f;  // (1/8)*log2(e)
    src[i] = f2bf(o1 * QSCL); src[i + 32] = f2bf(o2 * QSCL);
  } else if (h == NH_) {               // K
    unsigned short* dst = Kr + (size_t)tok * HD_;
    dst[i] = f2bf(o1); dst[i + 32] = f2bf(o2);
  } else {                             // V transposed
    Vt[((size_t)b * HD_ + i) * S_ + s]      = f2bf(o1);
    Vt[((size_t)b * HD_ + i + 32) * S_ + s] = f2bf(o2);
  }
}

// ---------------- causal flash attention (MQA) ----------------
// grid (8, B*NH). block 256 = 4 waves. Each block processes two q-tiles
// {p, 15-p} of 128 rows (balanced causal work: 34 KV rounds/block).
// K/V LDS double-buffered; next tile staged before compute (2-phase pipeline).
__global__ __launch_bounds__(256) void k_attn(const unsigned short* __restrict__ fused,
                                              const unsigned short* __restrict__ Kr,
                                              const unsigned short* __restrict__ Vt,
                                              unsigned short* __restrict__ ctx) {
  __shared__ unsigned short Ks[2][64 * 64];  // 16 KB, swizzled
  __shared__ unsigned short Vs[2][64 * 64];  // 16 KB, swizzled
  __shared__ unsigned short Ps[4][16 * 64];  // 8 KB per-wave P, swizzled
  const int tid  = threadIdx.x;
  const int lane = tid & 63;
  const int w    = tid >> 6;
  const int p    = blockIdx.x;     // pair index 0..7
  const int bh   = blockIdx.y;
  const int b    = bh >> 5;
  const int h    = bh & 31;
  const int g    = lane >> 4;      // lane group 0..3
  const int cidx = lane & 15;
  const int rbase = g * 4;

  // staging pattern: per round r (32 rows), wave w stages rows r*32 + w*8 + sr
  const int sr = lane >> 3;                  // 0..7
  const int sc = (((lane & 7) ^ sr)) * 8;    // swizzled source chunk

  for (int side = 0; side < 2; ++side) {
    const int qt = side ? (15 - p) : p;
    const int q0 = qt * 128;
    const int nt = 2 * qt + 2;

    // Q fragments for this q-tile
    bf16x8 aq[2][2];
#pragma unroll
    for (int rg = 0; rg < 2; ++rg) {
      const unsigned short* qb =
          fused + ((size_t)(b * S_ + q0 + w * 32 + rg * 16 + cidx)) * FDIM + h * HD_ + g * 8;
      aq[rg][0] = *reinterpret_cast<const bf16x8*>(qb);
      aq[rg][1] = *reinterpret_cast<const bf16x8*>(qb + 32);
    }

    f32x4 oacc[2][4] = {};
    float mrun[2][4], lsum[2][4];
#pragma unroll
    for (int rg = 0; rg < 2; ++rg)
#pragma unroll
      for (int r = 0; r < 4; ++r) { mrun[rg][r] = -1e30f; lsum[rg][r] = 0.f; }

    if (side) __syncthreads();  // protect buf0 from previous side's readers

    // prologue: stage tile 0 into buf 0
#pragma unroll
    for (int r = 0; r < 2; ++r) {
      int row = r * 32 + w * 8 + sr;
      gload_lds16(Kr + ((size_t)(b * S_ + row)) * HD_ + sc,
                  (char*)Ks + r * 4096 + w * 1024);
      gload_lds16(Vt + ((size_t)(b * HD_ + row)) * S_ + sc,
                  (char*)Vs + r * 4096 + w * 1024);
    }

    int buf = 0;
    for (int t = 0; t < nt; ++t) {
      __syncthreads();   // drains my vmem -> buf's tile ready for all waves

      if (t + 1 < nt) {  // prefetch next tile into alt buffer (stays in flight)
        const int kv1 = (t + 1) * 64;
#pragma unroll
        for (int r = 0; r < 2; ++r) {
          int row = r * 32 + w * 8 + sr;
          gload_lds16(Kr + ((size_t)(b * S_ + kv1 + row)) * HD_ + sc,
                      (char*)Ks + (buf ^ 1) * 8192 + r * 4096 + w * 1024);
          gload_lds16(Vt + ((size_t)(b * HD_ + row)) * S_ + kv1 + sc,
                      (char*)Vs + (buf ^ 1) * 8192 + r * 4096 + w * 1024);
        }
      }

      const int kv0 = t * 64;
      const unsigned short* Kcur = (const unsigned short*)((const char*)Ks + buf * 8192);
      const unsigned short* Vcur = (const unsigned short*)((const char*)Vs + buf * 8192);
      buf ^= 1;

#pragma unroll
      for (int rg = 0; rg < 2; ++rg) {
        const int rowTop = q0 + w * 32 + rg * 16;
        if (kv0 > rowTop + 15) continue;   // fully masked row-group (wave-uniform)

        // S = (Q*scl) K^T  (scale folded into Q)
        f32x4 sacc[4];
        __builtin_amdgcn_s_setprio(1);
#pragma unroll
        for (int ni = 0; ni < 4; ++ni) {
          int krow = ni * 16 + cidx;
          bf16x8 bk0 = lds_rd_swz(Kcur, krow, g);
          bf16x8 bk1 = lds_rd_swz(Kcur, krow, 4 + g);
          f32x4 z = {};
          z = __builtin_amdgcn_mfma_f32_16x16x32_bf16(aq[rg][0], bk0, z, 0, 0, 0);
          z = __builtin_amdgcn_mfma_f32_16x16x32_bf16(aq[rg][1], bk1, z, 0, 0, 0);
          sacc[ni] = z;
        }
        __builtin_amdgcn_s_setprio(0);

        const bool needMask = (kv0 + 63 > rowTop);  // wave-uniform
        float tmax[4];
#pragma unroll
        for (int r = 0; r < 4; ++r) {
          float mx = -1e30f;
          if (needMask) {
            int row = rowTop + rbase + r;
#pragma unroll
            for (int ni = 0; ni < 4; ++ni) {
              int col = kv0 + ni * 16 + cidx;
              float v = (col <= row) ? sacc[ni][r] : -1e30f;
              sacc[ni][r] = v;
              mx = fmaxf(mx, v);
            }
          } else {
#pragma unroll
            for (int ni = 0; ni < 4; ++ni)
              mx = fmaxf(mx, sacc[ni][r]);
          }
#pragma unroll
          for (int off = 1; off < 16; off <<= 1)
            mx = fmaxf(mx, __shfl_xor(mx, off));
          tmax[r] = mx;
        }

        // defer-max (T13): skip O-rescale if max didn't grow past threshold
        bool ok = true;
#pragma unroll
        for (int r = 0; r < 4; ++r) ok = ok && (tmax[r] <= mrun[rg][r] + 8.0f);
        if (__all(ok)) {
#pragma unroll
          for (int r = 0; r < 4; ++r) {
            float m = mrun[rg][r];
            float rsum = 0.f;
#pragma unroll
            for (int ni = 0; ni < 4; ++ni) {
              float pv = __builtin_amdgcn_exp2f(sacc[ni][r] - m);
              sacc[ni][r] = pv;
              rsum += pv;
            }
#pragma unroll
            for (int off = 1; off < 16; off <<= 1)
              rsum += __shfl_xor(rsum, off);
            lsum[rg][r] += rsum;
          }
        } else {
#pragma unroll
          for (int r = 0; r < 4; ++r) {
            float mnew = fmaxf(mrun[rg][r], tmax[r]);
            float corr = __builtin_amdgcn_exp2f(mrun[rg][r] - mnew);
            mrun[rg][r] = mnew;
            float rsum = 0.f;
#pragma unroll
            for (int ni = 0; ni < 4; ++ni) {
              float pv = __builtin_amdgcn_exp2f(sacc[ni][r] - mnew);
              sacc[ni][r] = pv;
              rsum += pv;
            }
#pragma unroll
            for (int off = 1; off < 16; off <<= 1)
              rsum += __shfl_xor(rsum, off);
            lsum[rg][r] = lsum[rg][r] * corr + rsum;
#pragma unroll
            for (int di = 0; di < 4; ++di)
              oacc[rg][di][r] *= corr;
          }
        }

        // P -> wave-private LDS (swizzled), then read back as A operand
        unsigned short* Pw = Ps[w];
#pragma unroll
        for (int ni = 0; ni < 4; ++ni)
#pragma unroll
          for (int r = 0; r < 4; ++r) {
            int prow = rbase + r;
            int col  = ni * 16 + cidx;
            Pw[prow * 64 + (col ^ ((prow & 7) << 3))] = f2bf(sacc[ni][r]);
          }
        bf16x8 ap0 = *reinterpret_cast<const bf16x8*>(&Pw[cidx * 64 + ((g ^ (cidx & 7)) << 3)]);
        bf16x8 ap1 = *reinterpret_cast<const bf16x8*>(&Pw[cidx * 64 + (((4 + g) ^ (cidx & 7)) << 3)]);

        __builtin_amdgcn_s_setprio(1);
#pragma unroll
        for (int di = 0; di < 4; ++di) {
          int vrow = di * 16 + cidx;
          bf16x8 bv0 = lds_rd_swz(Vcur, vrow, g);
          bf16x8 bv1 = lds_rd_swz(Vcur, vrow, 4 + g);
          oacc[rg][di] = __builtin_amdgcn_mfma_f32_16x16x32_bf16(ap0, bv0, oacc[rg][di], 0, 0, 0);
          oacc[rg][di] = __builtin_amdgcn_mfma_f32_16x16x32_bf16(ap1, bv1, oacc[rg][di], 0, 0, 0);
        }
        __builtin_amdgcn_s_setprio(0);
      }
    }

    // epilogue: ctx[b, s, h*64+d] = O / l
#pragma unroll
    for (int rg = 0; rg < 2; ++rg)
#pragma unroll
      for (int di = 0; di < 4; ++di)
#pragma unroll
        for (int r = 0; r < 4; ++r) {
          int row = q0 + w * 32 + rg * 16 + rbase + r;
          int d   = di * 16 + cidx;
          ctx[((size_t)(b * S_ + row)) * HID_ + h * HD_ + d] =
              f2bf(oacc[rg][di][r] / lsum[rg][r]);
        }
  }
}

// ---------------- launch ----------------
extern "C" void kernel_launch(void* const* d_in, const int* in_sizes, int n_in,
                              void* d_out, int out_size, void* d_ws, size_t ws_size,
                              hipStream_t stream) {
  const float* hidden  = (const float*)d_in[0];
  const float* w_qkv   = (const float*)d_in[1];
  const float* w_dense = (const float*)d_in[2];
  char* ws = (char*)d_ws;

  // workspace layout (bytes)
  unsigned short* Xb  = (unsigned short*)(ws + 0);          // 4096x2048 bf16 (reused as ctx)
  unsigned short* Wqb = (unsigned short*)(ws + 16777216);   // 2176x2048 bf16
  unsigned short* Wdb = (unsigned short*)(ws + 25690112);   // 2048x2048 bf16
  unsigned short* Fb  = (unsigned short*)(ws + 34078720);   // 4096x2176 bf16 (fused QKV)
  unsigned short* Kr  = (unsigned short*)(ws + 51904512);   // 2x2048x64 bf16
  unsigned short* Vt  = (unsigned short*)(ws + 52428800);   // 2x64x2048 bf16

  const int n1 = B_ * S_ * HID_;   // 8388608
  const int n2 = FDIM * HID_;      // 4456448
  const int n3 = HID_ * HID_;      // 4194304
  k_f32_to_bf16<<<dim3((n1 / 4 + 255) / 256), 256, 0, stream>>>(hidden, Xb, n1);
  k_f32_to_bf16<<<dim3((n2 / 4 + 255) / 256), 256, 0, stream>>>(w_qkv, Wqb, n2);
  k_f32_to_bf16<<<dim3((n3 / 4 + 255) / 256), 256, 0, stream>>>(w_dense, Wdb, n3);

  // fused = X @ Wqkv^T  (M=4096, N=2176, K=2048), bf16 out
  k_gemm_bt<1><<<dim3(FDIM / 128, (B_ * S_) / 128), 256, 0, stream>>>(
      Xb, Wqb, (void*)Fb, B_ * S_, FDIM, HID_);

  // RoPE (Q in place + folded softmax scale, K->Kr, V->Vt)
  const int nrope = B_ * S_ * NQKV * 32;
  k_rope<<<dim3(nrope / 256), 256, 0, stream>>>(Fb, Kr, Vt);

  // attention -> ctx (reuses Xb)
  k_attn<<<dim3(8, B_ * NH_), 256, 0, stream>>>(Fb, Kr, Vt, Xb);

  // out = ctx @ Wd^T  (M=4096, N=2048, K=2048), fp32 out
  k_gemm_bt<0><<<dim3(HID_ / 128, (B_ * S_) / 128), 256, 0, stream>>>(
      Xb, Wdb, d_out, B_ * S_, HID_, HID_);
}

// Round 4
// 232.499 us; speedup vs baseline: 1.8631x; 1.2681x over previous
//
#include <hip/hip_runtime.h>
#include <hip/hip_bf16.h>
#include <cstdint>
#include <cmath>

// Problem constants
#define B_    2
#define S_    2048
#define HID_  2048
#define NH_   32
#define HD_   64
#define NQKV  34        // NH + 2
#define FDIM  2176      // NQKV * HD

typedef __attribute__((ext_vector_type(8)))  __bf16 bf16x8;
typedef __attribute__((ext_vector_type(4)))  float  f32x4;
typedef __attribute__((ext_vector_type(16))) float  f32x16;

__device__ __forceinline__ unsigned short f2bf(float f) {
  union { float f; uint32_t u; } v; v.f = f;
  return (unsigned short)((v.u + 0x7FFFu + ((v.u >> 16) & 1u)) >> 16);  // RNE
}
__device__ __forceinline__ float bf2f(unsigned short h) {
  union { uint32_t u; float f; } v; v.u = ((uint32_t)h) << 16;
  return v.f;
}
// pack two f32 -> u32 of 2 bf16 (compiler emits v_cvt_pk_bf16_f32 on gfx950)
__device__ __forceinline__ uint32_t pkbf(float lo, float hi) {
  union { __bf16 h[2]; uint32_t u; } z;
  z.h[0] = (__bf16)lo; z.h[1] = (__bf16)hi;
  return z.u;
}

// async global->LDS, 16B per lane. LDS dest is wave-uniform base + lane*16.
__device__ __forceinline__ void gload_lds16(const void* g, void* lds) {
  __builtin_amdgcn_global_load_lds(
      (const __attribute__((address_space(1))) uint32_t*)(uintptr_t)g,
      (__attribute__((address_space(3))) uint32_t*)(uint32_t)(uintptr_t)lds,
      16, 0, 0);
}

// swizzled LDS 16B read from a [rows][64] bf16 tile (128B rows):
// chunk c in [0,8), actual chunk = c ^ (row&7)
__device__ __forceinline__ bf16x8 lds_rd_swz(const unsigned short* tile, int row, int c) {
  return *reinterpret_cast<const bf16x8*>(
      reinterpret_cast<const char*>(tile) + row * 128 + ((c ^ (row & 7)) << 4));
}

// ---------------- fp32 -> bf16 convert (vectorized) ----------------
__global__ void k_f32_to_bf16(const float* __restrict__ in,
                              unsigned short* __restrict__ out, int n) {
  int i = blockIdx.x * blockDim.x + threadIdx.x;
  int n4 = n >> 2;
  if (i < n4) {
    float4 f = reinterpret_cast<const float4*>(in)[i];
    ushort4 o;
    o.x = f2bf(f.x); o.y = f2bf(f.y); o.z = f2bf(f.z); o.w = f2bf(f.w);
    reinterpret_cast<ushort4*>(out)[i] = o;
  }
}

// ---------------- bf16 GEMM: C[M,N] = A[M,K] * B[N,K]^T ----------------
template<int WRITE_BF16>
__global__ __launch_bounds__(256) void k_gemm_bt(const unsigned short* __restrict__ A,
                                                 const unsigned short* __restrict__ Bm,
                                                 void* __restrict__ Cout,
                                                 int M, int N, int K) {
  __shared__ unsigned short As[128][32];   // 8 KB
  __shared__ unsigned short Bs[128][32];   // 8 KB
  const int tid  = threadIdx.x;
  const int lane = tid & 63;
  const int wave = tid >> 6;
  const int wr = wave >> 1, wc = wave & 1;
  const int bm = blockIdx.y, bn = blockIdx.x;

  f32x4 acc[4][4] = {};

  const unsigned short* gA = A  + (size_t)bm * 128 * K;
  const unsigned short* gB = Bm + (size_t)bn * 128 * K;
  const int srow = wave * 16 + (lane >> 2);
  const int scol = (lane & 3) * 8;

  for (int k0 = 0; k0 < K; k0 += 32) {
    __syncthreads();
#pragma unroll
    for (int r = 0; r < 2; ++r) {
      gload_lds16(gA + (size_t)(srow + r * 64) * K + k0 + scol,
                  (char*)(&As[0][0]) + r * 4096 + wave * 1024);
      gload_lds16(gB + (size_t)(srow + r * 64) * K + k0 + scol,
                  (char*)(&Bs[0][0]) + r * 4096 + wave * 1024);
    }
    __syncthreads();

    bf16x8 af[4], bfr[4];
#pragma unroll
    for (int i = 0; i < 4; ++i) {
      af[i]  = *reinterpret_cast<const bf16x8*>(&As[wr * 64 + i * 16 + (lane & 15)][(lane >> 4) * 8]);
      bfr[i] = *reinterpret_cast<const bf16x8*>(&Bs[wc * 64 + i * 16 + (lane & 15)][(lane >> 4) * 8]);
    }
#pragma unroll
    for (int i = 0; i < 4; ++i)
#pragma unroll
      for (int j = 0; j < 4; ++j)
        acc[i][j] = __builtin_amdgcn_mfma_f32_16x16x32_bf16(af[i], bfr[j], acc[i][j], 0, 0, 0);
  }

  const int rbase = (lane >> 4) * 4;
  const int cbase = lane & 15;
#pragma unroll
  for (int i = 0; i < 4; ++i)
#pragma unroll
    for (int j = 0; j < 4; ++j)
#pragma unroll
      for (int r = 0; r < 4; ++r) {
        int row = bm * 128 + wr * 64 + i * 16 + rbase + r;
        int col = bn * 128 + wc * 64 + j * 16 + cbase;
        if (WRITE_BF16)
          ((unsigned short*)Cout)[(size_t)row * N + col] = f2bf(acc[i][j][r]);
        else
          ((float*)Cout)[(size_t)row * N + col] = acc[i][j][r];
      }
}

// ---------------- RoPE + split ----------------
// Q additionally pre-scaled by 0.125*log2(e) so attention softmax can use raw exp2.
__global__ void k_rope(unsigned short* __restrict__ fused,
                       unsigned short* __restrict__ Kr,
                       unsigned short* __restrict__ Vt) {
  int idx = blockIdx.x * blockDim.x + threadIdx.x;  // (tok, h, i): i in [0,32)
  if (idx >= B_ * S_ * NQKV * 32) return;
  int i   = idx & 31;
  int h   = (idx >> 5) % NQKV;
  int tok = idx / (32 * NQKV);
  int s   = tok & (S_ - 1);
  int b   = tok >> 11;

  unsigned short* src = fused + (size_t)tok * FDIM + h * HD_;
  float x1 = bf2f(src[i]);
  float x2 = bf2f(src[i + 32]);
  float o1, o2;
  if (h <= NH_) {  // q heads + k head
    float ang = (float)s * expf(-(float)i * 0.2878231366242557f /* ln(1e4)/32 */);
    float sn, cs;
    sincosf(ang, &sn, &cs);
    o1 = x1 * cs - x2 * sn;
    o2 = x2 * cs + x1 * sn;
  } else { o1 = x1; o2 = x2; }

  if (h < NH_) {                       // Q in place, folded softmax scale
    const float QSCL = 0.18033688011112042f;  // (1/8)*log2(e)
    src[i] = f2bf(o1 * QSCL); src[i + 32] = f2bf(o2 * QSCL);
  } else if (h == NH_) {               // K
    unsigned short* dst = Kr + (size_t)tok * HD_;
    dst[i] = f2bf(o1); dst[i + 32] = f2bf(o2);
  } else {                             // V transposed
    Vt[((size_t)b * HD_ + i) * S_ + s]      = f2bf(o1);
    Vt[((size_t)b * HD_ + i + 32) * S_ + s] = f2bf(o2);
  }
}

// ---------------- causal flash attention (MQA), swapped-QK^T in-register softmax ----
// grid (8, B*NH). block 256 = 4 waves; wave w owns 32 q rows of a 128-row tile.
// Each block processes q-tiles {p, 15-p} (balanced: 34 KV rounds).
// S^T = mfma32(K_frag, Q_frag): lane holds P-row for q = lane&31 (half per partner).
__global__ __launch_bounds__(256) void k_attn(const unsigned short* __restrict__ fused,
                                              const unsigned short* __restrict__ Kr,
                                              const unsigned short* __restrict__ Vt,
                                              unsigned short* __restrict__ ctx) {
  __shared__ unsigned short Ks[2][64 * 64];  // 16 KB, swizzled
  __shared__ unsigned short Vs[2][64 * 64];  // 16 KB, swizzled
  const int tid  = threadIdx.x;
  const int lane = tid & 63;
  const int w    = tid >> 6;
  const int p    = blockIdx.x;     // pair index 0..7
  const int bh   = blockIdx.y;
  const int b    = bh >> 5;
  const int h    = bh & 31;
  const int ql   = lane & 31;      // q column (this lane's q row)
  const int hi   = lane >> 5;      // 0/1: k-chunk / row-offset group

  // staging pattern (as R3): per round r (32 rows), wave w stages rows r*32+w*8+sr
  const int sr = lane >> 3;                  // 0..7
  const int sc = (((lane & 7) ^ sr)) * 8;    // swizzled source chunk

  for (int side = 0; side < 2; ++side) {
    const int qt = side ? (15 - p) : p;
    const int q0 = qt * 128;
    const int nt = 2 * qt + 2;
    const int qrow  = q0 + w * 32 + ql;
    const int qlo_w = q0 + w * 32;
    const int qhi_w = qlo_w + 31;

    // Q B-fragments: col=ql, k-chunk hi*8, 4 d-slabs of 16
    bf16x8 qf[4];
    {
      const unsigned short* qb =
          fused + ((size_t)(b * S_ + qrow)) * FDIM + h * HD_ + hi * 8;
#pragma unroll
      for (int s = 0; s < 4; ++s)
        qf[s] = *reinterpret_cast<const bf16x8*>(qb + s * 16);
    }

    f32x16 oacc0 = {}, oacc1 = {};
    float mrun = -1e30f, lsum = 0.f;

    if (side) __syncthreads();  // all waves done with previous side's buffers

    // prologue: stage tile 0 into buf 0
#pragma unroll
    for (int r = 0; r < 2; ++r) {
      int row = r * 32 + w * 8 + sr;
      gload_lds16(Kr + ((size_t)(b * S_ + row)) * HD_ + sc,
                  (char*)Ks + r * 4096 + w * 1024);
      gload_lds16(Vt + ((size_t)(b * HD_ + row)) * S_ + sc,
                  (char*)Vs + r * 4096 + w * 1024);
    }

    int buf = 0;
    for (int t = 0; t < nt; ++t) {
      __syncthreads();   // drains vmem -> buf's tile ready for all waves

      if (t + 1 < nt) {  // prefetch next tile into alt buffer (stays in flight)
        const int kv1 = (t + 1) * 64;
#pragma unroll
        for (int r = 0; r < 2; ++r) {
          int row = r * 32 + w * 8 + sr;
          gload_lds16(Kr + ((size_t)(b * S_ + kv1 + row)) * HD_ + sc,
                      (char*)Ks + (buf ^ 1) * 8192 + r * 4096 + w * 1024);
          gload_lds16(Vt + ((size_t)(b * HD_ + row)) * S_ + kv1 + sc,
                      (char*)Vs + (buf ^ 1) * 8192 + r * 4096 + w * 1024);
        }
      }

      const int kv0 = t * 64;
      const unsigned short* Kcur = (const unsigned short*)((const char*)Ks + buf * 8192);
      const unsigned short* Vcur = (const unsigned short*)((const char*)Vs + buf * 8192);
      buf ^= 1;

      if (kv0 > qhi_w) continue;   // fully masked for this wave (uniform)

      // S^T[kv][q] = K · Q^T  (scale folded into Q), two 32-kv halves
      f32x16 sh[2];
      __builtin_amdgcn_s_setprio(1);
#pragma unroll
      for (int half = 0; half < 2; ++half) {
        f32x16 z = {};
#pragma unroll
        for (int s = 0; s < 4; ++s) {
          bf16x8 kf = lds_rd_swz(Kcur, half * 32 + ql, s * 2 + hi);
          z = __builtin_amdgcn_mfma_f32_32x32x16_bf16(kf, qf[s], z, 0, 0, 0);
        }
        sh[half] = z;
      }
      __builtin_amdgcn_s_setprio(0);

      // causal mask (diagonal tiles only). kv = kv0 + half*32 + (r&3)+8*(r>>2)+4*hi
      if (kv0 + 63 > qlo_w) {
#pragma unroll
        for (int half = 0; half < 2; ++half) {
          const int thr = qrow - kv0 - half * 32 - 4 * hi;
#pragma unroll
          for (int r = 0; r < 16; ++r) {
            const int kvo = (r & 3) + 8 * (r >> 2);
            sh[half][r] = (kvo <= thr) ? sh[half][r] : -1e30f;
          }
        }
      }

      // row max: in-register tree (32 vals) + partner exchange
      float mx;
      {
        float t16[16];
#pragma unroll
        for (int r = 0; r < 16; ++r) t16[r] = fmaxf(sh[0][r], sh[1][r]);
#pragma unroll
        for (int st = 8; st >= 1; st >>= 1)
#pragma unroll
          for (int r = 0; r < st; ++r) t16[r] = fmaxf(t16[r], t16[r + st]);
        mx = fmaxf(t16[0], __shfl_xor(t16[0], 32));
      }

      // defer-max (T13)
      float mcur;
      bool ok = (mx <= mrun + 8.0f);
      if (__all(ok)) {
        mcur = mrun;
      } else {
        float mnew = fmaxf(mrun, mx);
        float corr = __builtin_amdgcn_exp2f(mrun - mnew);
        mrun = mnew; mcur = mnew;
        lsum *= corr;
#pragma unroll
        for (int r = 0; r < 16; ++r) { oacc0[r] *= corr; oacc1[r] *= corr; }
      }

      // exp2 in place + row sum (tree + partner)
#pragma unroll
      for (int half = 0; half < 2; ++half)
#pragma unroll
        for (int r = 0; r < 16; ++r)
          sh[half][r] = __builtin_amdgcn_exp2f(sh[half][r] - mcur);
      {
        float t16[16];
#pragma unroll
        for (int r = 0; r < 16; ++r) t16[r] = sh[0][r] + sh[1][r];
#pragma unroll
        for (int st = 8; st >= 1; st >>= 1)
#pragma unroll
          for (int r = 0; r < st; ++r) t16[r] += t16[r + st];
        lsum += t16[0] + __shfl_xor(t16[0], 32);
      }

      // pack P -> B-operand fragments per kv-slab of 16 (T12 exchange)
      // lane owns kv_off {0..3,8..11}+4hi per slab; B-frag needs 8 consecutive at hi*8
      bf16x8 pf[4];
#pragma unroll
      for (int slab = 0; slab < 4; ++slab) {
        const int half = slab >> 1, j = slab & 1;
        uint32_t a0 = pkbf(sh[half][8 * j + 0], sh[half][8 * j + 1]);
        uint32_t a1 = pkbf(sh[half][8 * j + 2], sh[half][8 * j + 3]);
        uint32_t b0 = pkbf(sh[half][8 * j + 4], sh[half][8 * j + 5]);
        uint32_t b1 = pkbf(sh[half][8 * j + 6], sh[half][8 * j + 7]);
        uint32_t s0 = hi ? a0 : b0;         // hi=0 sends b (kv 8..11), hi=1 sends a (kv 4..7)
        uint32_t s1 = hi ? a1 : b1;
        uint32_t r0 = __shfl_xor(s0, 32);
        uint32_t r1 = __shfl_xor(s1, 32);
        union { uint32_t wd[4]; bf16x8 v; } bw;
        bw.wd[0] = hi ? r0 : a0;
        bw.wd[1] = hi ? r1 : a1;
        bw.wd[2] = hi ? b0 : r0;
        bw.wd[3] = hi ? b1 : r1;
        pf[slab] = bw.v;
      }

      // O^T[d][q] += V^T · P^T : A = V^T rows d (2 blocks of 32), k = kv
      __builtin_amdgcn_s_setprio(1);
#pragma unroll
      for (int slab = 0; slab < 4; ++slab) {
        bf16x8 vf0 = lds_rd_swz(Vcur, ql,      slab * 2 + hi);
        bf16x8 vf1 = lds_rd_swz(Vcur, 32 + ql, slab * 2 + hi);
        oacc0 = __builtin_amdgcn_mfma_f32_32x32x16_bf16(vf0, pf[slab], oacc0, 0, 0, 0);
        oacc1 = __builtin_amdgcn_mfma_f32_32x32x16_bf16(vf1, pf[slab], oacc1, 0, 0, 0);
      }
      __builtin_amdgcn_s_setprio(0);
    }

    // epilogue: ctx[b, qrow, h*64 + d] = O^T[d][q] / l, d = dblk*32+(r&3)+8*(r>>2)+4*hi
    float inv = 1.0f / lsum;
    unsigned short* cb = ctx + ((size_t)(b * S_ + qrow)) * HID_ + h * HD_;
#pragma unroll
    for (int dblk = 0; dblk < 2; ++dblk) {
#pragma unroll
      for (int r = 0; r < 16; r += 2) {
        float e0 = (dblk ? oacc1[r]     : oacc0[r])     * inv;
        float e1 = (dblk ? oacc1[r + 1] : oacc0[r + 1]) * inv;
        int d = dblk * 32 + (r & 3) + 8 * (r >> 2) + 4 * hi;
        *reinterpret_cast<uint32_t*>(cb + d) = pkbf(e0, e1);
      }
    }
  }
}

// ---------------- launch ----------------
extern "C" void kernel_launch(void* const* d_in, const int* in_sizes, int n_in,
                              void* d_out, int out_size, void* d_ws, size_t ws_size,
                              hipStream_t stream) {
  const float* hidden  = (const float*)d_in[0];
  const float* w_qkv   = (const float*)d_in[1];
  const float* w_dense = (const float*)d_in[2];
  char* ws = (char*)d_ws;

  // workspace layout (bytes)
  unsigned short* Xb  = (unsigned short*)(ws + 0);          // 4096x2048 bf16 (reused as ctx)
  unsigned short* Wqb = (unsigned short*)(ws + 16777216);   // 2176x2048 bf16
  unsigned short* Wdb = (unsigned short*)(ws + 25690112);   // 2048x2048 bf16
  unsigned short* Fb  = (unsigned short*)(ws + 34078720);   // 4096x2176 bf16 (fused QKV)
  unsigned short* Kr  = (unsigned short*)(ws + 51904512);   // 2x2048x64 bf16
  unsigned short* Vt  = (unsigned short*)(ws + 52428800);   // 2x64x2048 bf16

  const int n1 = B_ * S_ * HID_;   // 8388608
  const int n2 = FDIM * HID_;      // 4456448
  const int n3 = HID_ * HID_;      // 4194304
  k_f32_to_bf16<<<dim3((n1 / 4 + 255) / 256), 256, 0, stream>>>(hidden, Xb, n1);
  k_f32_to_bf16<<<dim3((n2 / 4 + 255) / 256), 256, 0, stream>>>(w_qkv, Wqb, n2);
  k_f32_to_bf16<<<dim3((n3 / 4 + 255) / 256), 256, 0, stream>>>(w_dense, Wdb, n3);

  // fused = X @ Wqkv^T  (M=4096, N=2176, K=2048), bf16 out
  k_gemm_bt<1><<<dim3(FDIM / 128, (B_ * S_) / 128), 256, 0, stream>>>(
      Xb, Wqb, (void*)Fb, B_ * S_, FDIM, HID_);

  // RoPE (Q in place + folded softmax scale, K->Kr, V->Vt)
  const int nrope = B_ * S_ * NQKV * 32;
  k_rope<<<dim3(nrope / 256), 256, 0, stream>>>(Fb, Kr, Vt);

  // attention -> ctx (reuses Xb)
  k_attn<<<dim3(8, B_ * NH_), 256, 0, stream>>>(Fb, Kr, Vt, Xb);

  // out = ctx @ Wd^T  (M=4096, N=2048, K=2048), fp32 out
  k_gemm_bt<0><<<dim3(HID_ / 128, (B_ * S_) / 128), 256, 0, stream>>>(
      Xb, Wdb, d_out, B_ * S_, HID_, HID_);
}

// Round 5
// 210.697 us; speedup vs baseline: 2.0559x; 1.1035x over previous
//
#include <hip/hip_runtime.h>
#include <hip/hip_bf16.h>
#include <cstdint>
#include <cmath>

// Problem constants
#define B_    2
#define S_    2048
#define HID_  2048
#define NH_   32
#define HD_   64
#define NQKV  34        // NH + 2
#define FDIM  2176      // NQKV * HD

typedef __attribute__((ext_vector_type(8)))  __bf16 bf16x8;
typedef __attribute__((ext_vector_type(4)))  float  f32x4;
typedef __attribute__((ext_vector_type(16))) float  f32x16;

__device__ __forceinline__ unsigned short f2bf(float f) {
  union { float f; uint32_t u; } v; v.f = f;
  return (unsigned short)((v.u + 0x7FFFu + ((v.u >> 16) & 1u)) >> 16);  // RNE
}
__device__ __forceinline__ float bf2f(unsigned short h) {
  union { uint32_t u; float f; } v; v.u = ((uint32_t)h) << 16;
  return v.f;
}
// pack two f32 -> u32 of 2 bf16 (compiler emits v_cvt_pk_bf16_f32 on gfx950)
__device__ __forceinline__ uint32_t pkbf(float lo, float hi) {
  union { __bf16 h[2]; uint32_t u; } z;
  z.h[0] = (__bf16)lo; z.h[1] = (__bf16)hi;
  return z.u;
}

// async global->LDS, 16B per lane. LDS dest is wave-uniform base + lane*16.
__device__ __forceinline__ void gload_lds16(const void* g, void* lds) {
  __builtin_amdgcn_global_load_lds(
      (const __attribute__((address_space(1))) uint32_t*)(uintptr_t)g,
      (__attribute__((address_space(3))) uint32_t*)(uint32_t)(uintptr_t)lds,
      16, 0, 0);
}

// swizzled LDS 16B read from a [rows][64] bf16 tile (128B rows):
// chunk c in [0,8), actual chunk = c ^ (row&7)
__device__ __forceinline__ bf16x8 lds_rd_swz(const unsigned short* tile, int row, int c) {
  return *reinterpret_cast<const bf16x8*>(
      reinterpret_cast<const char*>(tile) + row * 128 + ((c ^ (row & 7)) << 4));
}

// ---------------- fp32 -> bf16 convert (vectorized) ----------------
__global__ void k_f32_to_bf16(const float* __restrict__ in,
                              unsigned short* __restrict__ out, int n) {
  int i = blockIdx.x * blockDim.x + threadIdx.x;
  int n4 = n >> 2;
  if (i < n4) {
    float4 f = reinterpret_cast<const float4*>(in)[i];
    ushort4 o;
    o.x = f2bf(f.x); o.y = f2bf(f.y); o.z = f2bf(f.z); o.w = f2bf(f.w);
    reinterpret_cast<ushort4*>(out)[i] = o;
  }
}

// ---------------- bf16 GEMM: C[M,N] = A[M,K] * B[N,K]^T ----------------
// BM=256, BN=128, BK=32; 512 threads = 8 waves (4M x 2N), 64x64 per wave.
// Counted-vmcnt 2-phase schedule (T3+T4): A-tile row-permuted so the phase-1
// rows (i<2, row bit5=0) and phase-2 rows are contiguous 8KB staging chunks.
//   storage s(row) = (row&31) | (((row>>6)&3)<<5) | (((row>>5)&1)<<7)
//   global  g(s)   = (s&31)   | (((s>>5)&3)<<6)   | (((s>>7)&1)<<5)
// Ledger per K-tile t: prologue/ph1(t-1) issued B(t),AE(t); ph2(t-1) issued AO(t).
//   entering ph1(t): vmcnt(1) -> B,AE landed, AO may fly
//   entering ph2(t): vmcnt(2) -> AO landed, keep B,AE(t+1)   (vmcnt(0) on last)
template<int WRITE_BF16>
__global__ __launch_bounds__(512) void k_gemm_bt(const unsigned short* __restrict__ A,
                                                 const unsigned short* __restrict__ Bm,
                                                 void* __restrict__ Cout,
                                                 int M, int N, int K) {
  __shared__ unsigned short As[2][256 * 32];   // 16 KB x2, permuted rows (64B each)
  __shared__ unsigned short Bs[2][128 * 32];   // 8 KB x2, plain rows
  const int tid  = threadIdx.x;
  const int lane = tid & 63;
  const int w    = tid >> 6;
  const int wm   = w >> 1, wn = w & 1;
  const int bn = blockIdx.x, bm = blockIdx.y;

  const unsigned short* gA = A  + (size_t)bm * 256 * K;
  const unsigned short* gB = Bm + (size_t)bn * 128 * K;

  // staging: round = 8KB = 128 rows x 64B; wave w covers storage rows w*16..w*16+15
  const int srow = w * 16 + (lane >> 2);
  const int scol = (lane & 3) * 8;
  const int gAE  = (srow & 31) | (((srow >> 5) & 3) << 6);   // g(s), s in [0,128)
  const int gAO  = gAE | 32;                                  // g(s+128)
  const size_t rB  = (size_t)srow * K + scol;
  const size_t rAE = (size_t)gAE  * K + scol;
  const size_t rAO = (size_t)gAO  * K + scol;
  const int ldsOff = w * 1024;

  // frag-read byte offsets (row permutation folded in for A)
  int offA[4], offB[4];
#pragma unroll
  for (int i = 0; i < 4; ++i) {
    int s = ((i & 1) << 4) | (lane & 15) | (wm << 5) | ((i >> 1) << 7);
    offA[i] = s * 64 + ((lane >> 4) << 4);
  }
#pragma unroll
  for (int j = 0; j < 4; ++j) {
    int s = wn * 64 + j * 16 + (lane & 15);
    offB[j] = s * 64 + ((lane >> 4) << 4);
  }

  f32x4 acc[4][4] = {};
  const int NT = K >> 5;

  // prologue: stage tile 0 (order matters: B, A_even, A_odd)
  gload_lds16(gB + rB,  (char*)Bs[0] + ldsOff);
  gload_lds16(gA + rAE, (char*)As[0] + ldsOff);
  gload_lds16(gA + rAO, (char*)As[0] + 8192 + ldsOff);

  for (int t = 0; t < NT; ++t) {
    const char* Ac = (const char*)As[t & 1];
    const char* Bc = (const char*)Bs[t & 1];
    char*       An = (char*)As[(t & 1) ^ 1];
    char*       Bn = (char*)Bs[(t & 1) ^ 1];
    const int  k1   = (t + 1) << 5;
    const bool more = (t + 1 < NT);

    // ---- phase 1: i = 0,1 (A_even) + all B ----
    asm volatile("s_waitcnt vmcnt(1)" ::: "memory");
    __builtin_amdgcn_s_barrier();
    asm volatile("" ::: "memory");
    bf16x8 b0 = *(const bf16x8*)(Bc + offB[0]);
    bf16x8 b1 = *(const bf16x8*)(Bc + offB[1]);
    bf16x8 b2 = *(const bf16x8*)(Bc + offB[2]);
    bf16x8 b3 = *(const bf16x8*)(Bc + offB[3]);
    bf16x8 a0 = *(const bf16x8*)(Ac + offA[0]);
    bf16x8 a1 = *(const bf16x8*)(Ac + offA[1]);
    if (more) {
      gload_lds16(gB + rB  + k1, Bn + ldsOff);
      gload_lds16(gA + rAE + k1, An + ldsOff);
    }
    __builtin_amdgcn_s_setprio(1);
    acc[0][0] = __builtin_amdgcn_mfma_f32_16x16x32_bf16(a0, b0, acc[0][0], 0, 0, 0);
    acc[0][1] = __builtin_amdgcn_mfma_f32_16x16x32_bf16(a0, b1, acc[0][1], 0, 0, 0);
    acc[0][2] = __builtin_amdgcn_mfma_f32_16x16x32_bf16(a0, b2, acc[0][2], 0, 0, 0);
    acc[0][3] = __builtin_amdgcn_mfma_f32_16x16x32_bf16(a0, b3, acc[0][3], 0, 0, 0);
    acc[1][0] = __builtin_amdgcn_mfma_f32_16x16x32_bf16(a1, b0, acc[1][0], 0, 0, 0);
    acc[1][1] = __builtin_amdgcn_mfma_f32_16x16x32_bf16(a1, b1, acc[1][1], 0, 0, 0);
    acc[1][2] = __builtin_amdgcn_mfma_f32_16x16x32_bf16(a1, b2, acc[1][2], 0, 0, 0);
    acc[1][3] = __builtin_amdgcn_mfma_f32_16x16x32_bf16(a1, b3, acc[1][3], 0, 0, 0);
    __builtin_amdgcn_s_setprio(0);

    // ---- phase 2: i = 2,3 (A_odd), B reused from registers ----
    if (more) { asm volatile("s_waitcnt vmcnt(2)" ::: "memory"); }
    else      { asm volatile("s_waitcnt vmcnt(0)" ::: "memory"); }
    __builtin_amdgcn_s_barrier();
    asm volatile("" ::: "memory");
    bf16x8 a2 = *(const bf16x8*)(Ac + offA[2]);
    bf16x8 a3 = *(const bf16x8*)(Ac + offA[3]);
    if (more) {
      gload_lds16(gA + rAO + k1, An + 8192 + ldsOff);
    }
    __builtin_amdgcn_s_setprio(1);
    acc[2][0] = __builtin_amdgcn_mfma_f32_16x16x32_bf16(a2, b0, acc[2][0], 0, 0, 0);
    acc[2][1] = __builtin_amdgcn_mfma_f32_16x16x32_bf16(a2, b1, acc[2][1], 0, 0, 0);
    acc[2][2] = __builtin_amdgcn_mfma_f32_16x16x32_bf16(a2, b2, acc[2][2], 0, 0, 0);
    acc[2][3] = __builtin_amdgcn_mfma_f32_16x16x32_bf16(a2, b3, acc[2][3], 0, 0, 0);
    acc[3][0] = __builtin_amdgcn_mfma_f32_16x16x32_bf16(a3, b0, acc[3][0], 0, 0, 0);
    acc[3][1] = __builtin_amdgcn_mfma_f32_16x16x32_bf16(a3, b1, acc[3][1], 0, 0, 0);
    acc[3][2] = __builtin_amdgcn_mfma_f32_16x16x32_bf16(a3, b2, acc[3][2], 0, 0, 0);
    acc[3][3] = __builtin_amdgcn_mfma_f32_16x16x32_bf16(a3, b3, acc[3][3], 0, 0, 0);
    __builtin_amdgcn_s_setprio(0);
  }

  // epilogue: C/D layout col=lane&15, row=(lane>>4)*4+reg
  const int rb = (lane >> 4) * 4;
  const int cb = lane & 15;
#pragma unroll
  for (int i = 0; i < 4; ++i)
#pragma unroll
    for (int j = 0; j < 4; ++j)
#pragma unroll
      for (int r = 0; r < 4; ++r) {
        int row = bm * 256 + wm * 64 + i * 16 + rb + r;
        int col = bn * 128 + wn * 64 + j * 16 + cb;
        if (WRITE_BF16)
          ((unsigned short*)Cout)[(size_t)row * N + col] = f2bf(acc[i][j][r]);
        else
          ((float*)Cout)[(size_t)row * N + col] = acc[i][j][r];
      }
}

// ---------------- RoPE + split ----------------
// Q additionally pre-scaled by 0.125*log2(e) so attention softmax can use raw exp2.
__global__ void k_rope(unsigned short* __restrict__ fused,
                       unsigned short* __restrict__ Kr,
                       unsigned short* __restrict__ Vt) {
  int idx = blockIdx.x * blockDim.x + threadIdx.x;  // (tok, h, i): i in [0,32)
  if (idx >= B_ * S_ * NQKV * 32) return;
  int i   = idx & 31;
  int h   = (idx >> 5) % NQKV;
  int tok = idx / (32 * NQKV);
  int s   = tok & (S_ - 1);
  int b   = tok >> 11;

  unsigned short* src = fused + (size_t)tok * FDIM + h * HD_;
  float x1 = bf2f(src[i]);
  float x2 = bf2f(src[i + 32]);
  float o1, o2;
  if (h <= NH_) {  // q heads + k head
    float ang = (float)s * expf(-(float)i * 0.2878231366242557f /* ln(1e4)/32 */);
    float sn, cs;
    sincosf(ang, &sn, &cs);
    o1 = x1 * cs - x2 * sn;
    o2 = x2 * cs + x1 * sn;
  } else { o1 = x1; o2 = x2; }

  if (h < NH_) {                       // Q in place, folded softmax scale
    const float QSCL = 0.18033688011112042f;  // (1/8)*log2(e)
    src[i] = f2bf(o1 * QSCL); src[i + 32] = f2bf(o2 * QSCL);
  } else if (h == NH_) {               // K
    unsigned short* dst = Kr + (size_t)tok * HD_;
    dst[i] = f2bf(o1); dst[i + 32] = f2bf(o2);
  } else {                             // V transposed
    Vt[((size_t)b * HD_ + i) * S_ + s]      = f2bf(o1);
    Vt[((size_t)b * HD_ + i + 32) * S_ + s] = f2bf(o2);
  }
}

// ---------------- causal flash attention (MQA), swapped-QK^T in-register softmax ----
// grid (8, B*NH). block 256 = 4 waves; wave w owns 32 q rows of a 128-row tile.
// Each block processes q-tiles {p, 15-p} (balanced: 34 KV rounds).
// S^T = mfma32(K_frag, Q_frag): lane holds P-row for q = lane&31 (half per partner).
__global__ __launch_bounds__(256) void k_attn(const unsigned short* __restrict__ fused,
                                              const unsigned short* __restrict__ Kr,
                                              const unsigned short* __restrict__ Vt,
                                              unsigned short* __restrict__ ctx) {
  __shared__ unsigned short Ks[2][64 * 64];  // 16 KB, swizzled
  __shared__ unsigned short Vs[2][64 * 64];  // 16 KB, swizzled
  const int tid  = threadIdx.x;
  const int lane = tid & 63;
  const int w    = tid >> 6;
  const int p    = blockIdx.x;     // pair index 0..7
  const int bh   = blockIdx.y;
  const int b    = bh >> 5;
  const int h    = bh & 31;
  const int ql   = lane & 31;      // q column (this lane's q row)
  const int hi   = lane >> 5;      // 0/1: k-chunk / row-offset group

  // staging pattern: per round r (32 rows), wave w stages rows r*32+w*8+sr
  const int sr = lane >> 3;                  // 0..7
  const int sc = (((lane & 7) ^ sr)) * 8;    // swizzled source chunk

  for (int side = 0; side < 2; ++side) {
    const int qt = side ? (15 - p) : p;
    const int q0 = qt * 128;
    const int nt = 2 * qt + 2;
    const int qrow  = q0 + w * 32 + ql;
    const int qlo_w = q0 + w * 32;
    const int qhi_w = qlo_w + 31;

    // Q B-fragments: col=ql, k-chunk hi*8, 4 d-slabs of 16
    bf16x8 qf[4];
    {
      const unsigned short* qb =
          fused + ((size_t)(b * S_ + qrow)) * FDIM + h * HD_ + hi * 8;
#pragma unroll
      for (int s = 0; s < 4; ++s)
        qf[s] = *reinterpret_cast<const bf16x8*>(qb + s * 16);
    }

    f32x16 oacc0 = {}, oacc1 = {};
    float mrun = -1e30f, lsum = 0.f;

    if (side) __syncthreads();  // all waves done with previous side's buffers

    // prologue: stage tile 0 into buf 0
#pragma unroll
    for (int r = 0; r < 2; ++r) {
      int row = r * 32 + w * 8 + sr;
      gload_lds16(Kr + ((size_t)(b * S_ + row)) * HD_ + sc,
                  (char*)Ks + r * 4096 + w * 1024);
      gload_lds16(Vt + ((size_t)(b * HD_ + row)) * S_ + sc,
                  (char*)Vs + r * 4096 + w * 1024);
    }

    int buf = 0;
    for (int t = 0; t < nt; ++t) {
      __syncthreads();   // drains vmem -> buf's tile ready for all waves

      if (t + 1 < nt) {  // prefetch next tile into alt buffer (stays in flight)
        const int kv1 = (t + 1) * 64;
#pragma unroll
        for (int r = 0; r < 2; ++r) {
          int row = r * 32 + w * 8 + sr;
          gload_lds16(Kr + ((size_t)(b * S_ + kv1 + row)) * HD_ + sc,
                      (char*)Ks + (buf ^ 1) * 8192 + r * 4096 + w * 1024);
          gload_lds16(Vt + ((size_t)(b * HD_ + row)) * S_ + kv1 + sc,
                      (char*)Vs + (buf ^ 1) * 8192 + r * 4096 + w * 1024);
        }
      }

      const int kv0 = t * 64;
      const unsigned short* Kcur = (const unsigned short*)((const char*)Ks + buf * 8192);
      const unsigned short* Vcur = (const unsigned short*)((const char*)Vs + buf * 8192);
      buf ^= 1;

      if (kv0 > qhi_w) continue;   // fully masked for this wave (uniform)

      // S^T[kv][q] = K · Q^T  (scale folded into Q), two 32-kv halves
      f32x16 sh[2];
      __builtin_amdgcn_s_setprio(1);
#pragma unroll
      for (int half = 0; half < 2; ++half) {
        f32x16 z = {};
#pragma unroll
        for (int s = 0; s < 4; ++s) {
          bf16x8 kf = lds_rd_swz(Kcur, half * 32 + ql, s * 2 + hi);
          z = __builtin_amdgcn_mfma_f32_32x32x16_bf16(kf, qf[s], z, 0, 0, 0);
        }
        sh[half] = z;
      }
      __builtin_amdgcn_s_setprio(0);

      // causal mask (diagonal tiles only). kv = kv0 + half*32 + (r&3)+8*(r>>2)+4*hi
      if (kv0 + 63 > qlo_w) {
#pragma unroll
        for (int half = 0; half < 2; ++half) {
          const int thr = qrow - kv0 - half * 32 - 4 * hi;
#pragma unroll
          for (int r = 0; r < 16; ++r) {
            const int kvo = (r & 3) + 8 * (r >> 2);
            sh[half][r] = (kvo <= thr) ? sh[half][r] : -1e30f;
          }
        }
      }

      // row max: in-register tree (32 vals) + partner exchange
      float mx;
      {
        float t16[16];
#pragma unroll
        for (int r = 0; r < 16; ++r) t16[r] = fmaxf(sh[0][r], sh[1][r]);
#pragma unroll
        for (int st = 8; st >= 1; st >>= 1)
#pragma unroll
          for (int r = 0; r < st; ++r) t16[r] = fmaxf(t16[r], t16[r + st]);
        mx = fmaxf(t16[0], __shfl_xor(t16[0], 32));
      }

      // defer-max (T13)
      float mcur;
      bool ok = (mx <= mrun + 8.0f);
      if (__all(ok)) {
        mcur = mrun;
      } else {
        float mnew = fmaxf(mrun, mx);
        float corr = __builtin_amdgcn_exp2f(mrun - mnew);
        mrun = mnew; mcur = mnew;
        lsum *= corr;
#pragma unroll
        for (int r = 0; r < 16; ++r) { oacc0[r] *= corr; oacc1[r] *= corr; }
      }

      // exp2 in place + row sum (tree + partner)
#pragma unroll
      for (int half = 0; half < 2; ++half)
#pragma unroll
        for (int r = 0; r < 16; ++r)
          sh[half][r] = __builtin_amdgcn_exp2f(sh[half][r] - mcur);
      {
        float t16[16];
#pragma unroll
        for (int r = 0; r < 16; ++r) t16[r] = sh[0][r] + sh[1][r];
#pragma unroll
        for (int st = 8; st >= 1; st >>= 1)
#pragma unroll
          for (int r = 0; r < st; ++r) t16[r] += t16[r + st];
        lsum += t16[0] + __shfl_xor(t16[0], 32);
      }

      // pack P -> B-operand fragments per kv-slab of 16 (T12 exchange)
      bf16x8 pf[4];
#pragma unroll
      for (int slab = 0; slab < 4; ++slab) {
        const int half = slab >> 1, j = slab & 1;
        uint32_t a0 = pkbf(sh[half][8 * j + 0], sh[half][8 * j + 1]);
        uint32_t a1 = pkbf(sh[half][8 * j + 2], sh[half][8 * j + 3]);
        uint32_t b0 = pkbf(sh[half][8 * j + 4], sh[half][8 * j + 5]);
        uint32_t b1 = pkbf(sh[half][8 * j + 6], sh[half][8 * j + 7]);
        uint32_t s0 = hi ? a0 : b0;         // hi=0 sends b (kv 8..11), hi=1 sends a (kv 4..7)
        uint32_t s1 = hi ? a1 : b1;
        uint32_t r0 = __shfl_xor(s0, 32);
        uint32_t r1 = __shfl_xor(s1, 32);
        union { uint32_t wd[4]; bf16x8 v; } bw;
        bw.wd[0] = hi ? r0 : a0;
        bw.wd[1] = hi ? r1 : a1;
        bw.wd[2] = hi ? b0 : r0;
        bw.wd[3] = hi ? b1 : r1;
        pf[slab] = bw.v;
      }

      // O^T[d][q] += V^T · P^T : A = V^T rows d (2 blocks of 32), k = kv
      __builtin_amdgcn_s_setprio(1);
#pragma unroll
      for (int slab = 0; slab < 4; ++slab) {
        bf16x8 vf0 = lds_rd_swz(Vcur, ql,      slab * 2 + hi);
        bf16x8 vf1 = lds_rd_swz(Vcur, 32 + ql, slab * 2 + hi);
        oacc0 = __builtin_amdgcn_mfma_f32_32x32x16_bf16(vf0, pf[slab], oacc0, 0, 0, 0);
        oacc1 = __builtin_amdgcn_mfma_f32_32x32x16_bf16(vf1, pf[slab], oacc1, 0, 0, 0);
      }
      __builtin_amdgcn_s_setprio(0);
    }

    // epilogue: ctx[b, qrow, h*64 + d] = O^T[d][q] / l, d = dblk*32+(r&3)+8*(r>>2)+4*hi
    float inv = 1.0f / lsum;
    unsigned short* cb = ctx + ((size_t)(b * S_ + qrow)) * HID_ + h * HD_;
#pragma unroll
    for (int dblk = 0; dblk < 2; ++dblk) {
#pragma unroll
      for (int r = 0; r < 16; r += 2) {
        float e0 = (dblk ? oacc1[r]     : oacc0[r])     * inv;
        float e1 = (dblk ? oacc1[r + 1] : oacc0[r + 1]) * inv;
        int d = dblk * 32 + (r & 3) + 8 * (r >> 2) + 4 * hi;
        *reinterpret_cast<uint32_t*>(cb + d) = pkbf(e0, e1);
      }
    }
  }
}

// ---------------- launch ----------------
extern "C" void kernel_launch(void* const* d_in, const int* in_sizes, int n_in,
                              void* d_out, int out_size, void* d_ws, size_t ws_size,
                              hipStream_t stream) {
  const float* hidden  = (const float*)d_in[0];
  const float* w_qkv   = (const float*)d_in[1];
  const float* w_dense = (const float*)d_in[2];
  char* ws = (char*)d_ws;

  // workspace layout (bytes)
  unsigned short* Xb  = (unsigned short*)(ws + 0);          // 4096x2048 bf16 (reused as ctx)
  unsigned short* Wqb = (unsigned short*)(ws + 16777216);   // 2176x2048 bf16
  unsigned short* Wdb = (unsigned short*)(ws + 25690112);   // 2048x2048 bf16
  unsigned short* Fb  = (unsigned short*)(ws + 34078720);   // 4096x2176 bf16 (fused QKV)
  unsigned short* Kr  = (unsigned short*)(ws + 51904512);   // 2x2048x64 bf16
  unsigned short* Vt  = (unsigned short*)(ws + 52428800);   // 2x64x2048 bf16

  const int n1 = B_ * S_ * HID_;   // 8388608
  const int n2 = FDIM * HID_;      // 4456448
  const int n3 = HID_ * HID_;      // 4194304
  k_f32_to_bf16<<<dim3((n1 / 4 + 255) / 256), 256, 0, stream>>>(hidden, Xb, n1);
  k_f32_to_bf16<<<dim3((n2 / 4 + 255) / 256), 256, 0, stream>>>(w_qkv, Wqb, n2);
  k_f32_to_bf16<<<dim3((n3 / 4 + 255) / 256), 256, 0, stream>>>(w_dense, Wdb, n3);

  // fused = X @ Wqkv^T  (M=4096, N=2176, K=2048), bf16 out. grid (N/128, M/256)
  k_gemm_bt<1><<<dim3(FDIM / 128, (B_ * S_) / 256), 512, 0, stream>>>(
      Xb, Wqb, (void*)Fb, B_ * S_, FDIM, HID_);

  // RoPE (Q in place + folded softmax scale, K->Kr, V->Vt)
  const int nrope = B_ * S_ * NQKV * 32;
  k_rope<<<dim3(nrope / 256), 256, 0, stream>>>(Fb, Kr, Vt);

  // attention -> ctx (reuses Xb)
  k_attn<<<dim3(8, B_ * NH_), 256, 0, stream>>>(Fb, Kr, Vt, Xb);

  // out = ctx @ Wd^T  (M=4096, N=2048, K=2048), fp32 out. grid (N/128, M/256)
  k_gemm_bt<0><<<dim3(HID_ / 128, (B_ * S_) / 256), 512, 0, stream>>>(
      Xb, Wdb, d_out, B_ * S_, HID_, HID_);
}